// Round 4
// baseline (323.666 us; speedup 1.0000x reference)
//
#include <hip/hip_runtime.h>
#include <hip/hip_bf16.h>

#define BB 64
#define JJ 32
#define NN 4096
#define QD 130
#define KD 128
#define VD 130
#define HH 4
#define PSTRIDE (JJ + JJ + JJ * VD)   // 4224 floats per partial block

typedef __attribute__((ext_vector_type(8)))  __bf16 bf16x8;
typedef __attribute__((ext_vector_type(16))) float  f32x16;

union BW { __bf16 b; unsigned short s; };
union FW4 { unsigned int u[4]; bf16x8 v; };

__device__ inline unsigned short bfbits(float x) {
    BW w; w.b = (__bf16)x; return w.s;
}

// ---------------------------------------------------------------- encoder ---
__global__ __launch_bounds__(64) void enc_kernel(
        const float* __restrict__ jq,
        const float* __restrict__ W1, const float* __restrict__ b1,
        const float* __restrict__ W2, const float* __restrict__ b2,
        float* __restrict__ qenc) {
    int row = blockIdx.x;          // b*J + j
    int t = threadIdx.x;           // 0..63
    __shared__ float x[QD];
    __shared__ float h[64];
    for (int i = t; i < QD; i += 64) x[i] = jq[row * QD + i];
    __syncthreads();
    float acc = b1[t];
    for (int i = 0; i < QD; ++i) acc += x[i] * W1[i * 64 + t];
    h[t] = fmaxf(acc, 0.f);
    __syncthreads();
    for (int s = 0; s < 8; ++s) {
        int o = t + 64 * s;
        float a = b2[o];
        for (int i = 0; i < 64; ++i) a += h[i] * W2[i * 512 + o];
        qenc[row * 512 + o] = a;
    }
}

// -------------------------------------------------------------- attention ---
// Block = (b, chunk of NN/CT keys). 4 waves = 4 heads. Split-bf16 MFMA:
// S^T = mfma(K, Q), P->A-frags in-register, O += mfma(P, V).
// LDS holds fragment-linear bf16 hi/lo K and V tiles.
template<int CT>
__global__ __launch_bounds__(256, 4) void attn_kernel(
        const float* __restrict__ Kg, const float* __restrict__ Vg,
        const int* __restrict__ maskg, const float* __restrict__ qenc,
        float* __restrict__ part) {
    constexpr int NCH = NN / CT;
    constexpr int TIL = NCH / 32;
    int blk = blockIdx.x;
    int c = blk & (CT - 1);
    int b = blk / CT;
    int tid = threadIdx.x;
    int wid = tid >> 6;            // head
    int lane = tid & 63;
    int l31 = lane & 31;
    int lh = lane >> 5;            // half-wave index

    // fragment-linear LDS: [plane hi/lo][kstep][lane][8 bf16]
    __shared__ __align__(16) __bf16 Kf[2][8][64][8];     // 16 KB
    __shared__ __align__(16) __bf16 Vf[2][10][64][8];    // 20 KB  (g = vt*2+ks)
    __shared__ float r_lds[4][32];

    // ---- Q B-fragments in registers (hi/lo), 8 k-steps
    bf16x8 qh[8], ql[8];
    {
        const float* qrow = qenc + (size_t)(b * JJ + l31) * 512 + wid * KD + lh * 8;
        #pragma unroll
        for (int kst = 0; kst < 8; ++kst) {
            float f[8];
            *(float4*)&f[0] = *(const float4*)(qrow + kst * 16);
            *(float4*)&f[4] = *(const float4*)(qrow + kst * 16 + 4);
            FW4 H, L;
            #pragma unroll
            for (int i = 0; i < 4; ++i) {
                __bf16 h0 = (__bf16)f[2 * i], h1 = (__bf16)f[2 * i + 1];
                BW w0, w1; w0.b = h0; w1.b = h1;
                H.u[i] = (unsigned int)w0.s | ((unsigned int)w1.s << 16);
                float r0 = f[2 * i] - (float)h0, r1 = f[2 * i + 1] - (float)h1;
                L.u[i] = (unsigned int)bfbits(r0) | ((unsigned int)bfbits(r1) << 16);
            }
            qh[kst] = H.v; ql[kst] = L.v;
        }
    }

    f32x16 O[5];
    #pragma unroll
    for (int vt = 0; vt < 5; ++vt)
        #pragma unroll
        for (int r = 0; r < 16; ++r) O[vt][r] = 0.f;
    float m_run = -1e30f, l_run = 0.f;

    const float* Kb = Kg + (size_t)b * NN * KD;
    const float* Vb = Vg + (size_t)b * NN * VD;
    const int*   Mb = maskg + b * NN;

    for (int t = 0; t < TIL; ++t) {
        int n0 = c * NCH + t * 32;
        __syncthreads();
        // ---- stage K fragments (512 positions, 2 per thread)
        #pragma unroll
        for (int pp = 0; pp < 2; ++pp) {
            int p = tid + pp * 256;
            int kst = p >> 6, sl = p & 63;
            const float* src = Kb + (size_t)(n0 + (sl & 31)) * KD + kst * 16 + (sl >> 5) * 8;
            float f[8];
            *(float4*)&f[0] = *(const float4*)(src);
            *(float4*)&f[4] = *(const float4*)(src + 4);
            FW4 H, L;
            #pragma unroll
            for (int i = 0; i < 4; ++i) {
                __bf16 h0 = (__bf16)f[2 * i], h1 = (__bf16)f[2 * i + 1];
                BW w0, w1; w0.b = h0; w1.b = h1;
                H.u[i] = (unsigned int)w0.s | ((unsigned int)w1.s << 16);
                float r0 = f[2 * i] - (float)h0, r1 = f[2 * i + 1] - (float)h1;
                L.u[i] = (unsigned int)bfbits(r0) | ((unsigned int)bfbits(r1) << 16);
            }
            *(bf16x8*)&Kf[0][kst][sl][0] = H.v;
            *(bf16x8*)&Kf[1][kst][sl][0] = L.v;
        }
        // ---- stage V fragments (640 positions)
        for (int p = tid; p < 640; p += 256) {
            int g = p >> 6, sl = p & 63;
            int vt = g >> 1, ks = g & 1;
            int v = vt * 32 + (sl & 31);
            int nr = n0 + ks * 16 + (sl >> 5) * 8;
            float f[8];
            #pragma unroll
            for (int j = 0; j < 8; ++j)
                f[j] = (v < VD) ? Vb[(size_t)(nr + j) * VD + v] : 0.f;
            FW4 H, L;
            #pragma unroll
            for (int i = 0; i < 4; ++i) {
                __bf16 h0 = (__bf16)f[2 * i], h1 = (__bf16)f[2 * i + 1];
                BW w0, w1; w0.b = h0; w1.b = h1;
                H.u[i] = (unsigned int)w0.s | ((unsigned int)w1.s << 16);
                float r0 = f[2 * i] - (float)h0, r1 = f[2 * i + 1] - (float)h1;
                L.u[i] = (unsigned int)bfbits(r0) | ((unsigned int)bfbits(r1) << 16);
            }
            *(bf16x8*)&Vf[0][g][sl][0] = H.v;
            *(bf16x8*)&Vf[1][g][sl][0] = L.v;
        }
        __syncthreads();

        // ---- mask word for this 32-key tile
        int mv = Mb[n0 + l31];
        unsigned int mword = (unsigned int)__ballot(mv != 0);

        // ---- S^T = K . Q  (3-term split)
        f32x16 S;
        #pragma unroll
        for (int r = 0; r < 16; ++r) S[r] = 0.f;
        #pragma unroll
        for (int kst = 0; kst < 8; ++kst) {
            bf16x8 kh = *(const bf16x8*)&Kf[0][kst][lane][0];
            bf16x8 kl = *(const bf16x8*)&Kf[1][kst][lane][0];
            S = __builtin_amdgcn_mfma_f32_32x32x16_bf16(kh, qh[kst], S, 0, 0, 0);
            S = __builtin_amdgcn_mfma_f32_32x32x16_bf16(kh, ql[kst], S, 0, 0, 0);
            S = __builtin_amdgcn_mfma_f32_32x32x16_bf16(kl, qh[kst], S, 0, 0, 0);
        }

        // ---- mask + scale, online softmax (per-lane column q = lane&31)
        const float sc = 0.08838834764831845f;
        float sp[16];
        float rm = -1e30f;
        #pragma unroll
        for (int r = 0; r < 16; ++r) {
            int key = (r & 3) + 8 * (r >> 2) + (lh << 2);
            float s = ((mword >> key) & 1u) ? -1e30f : S[r] * sc;
            sp[r] = s;
            rm = fmaxf(rm, s);
        }
        rm = fmaxf(rm, __shfl_xor(rm, 32));
        float mn = fmaxf(m_run, rm);
        float rs = __expf(m_run - mn);
        m_run = mn;
        float ps = 0.f;
        #pragma unroll
        for (int r = 0; r < 16; ++r) {
            float p = __expf(sp[r] - mn);
            sp[r] = p;
            ps += p;
        }
        ps += __shfl_xor(ps, 32);
        l_run = l_run * rs + ps;

        if (lane < 32) r_lds[wid][lane] = rs;
        if (!__all(rs == 1.0f)) {
            float rr[16];
            #pragma unroll
            for (int r = 0; r < 16; ++r)
                rr[r] = r_lds[wid][(r & 3) + 8 * (r >> 2) + (lh << 2)];
            #pragma unroll
            for (int vt = 0; vt < 5; ++vt)
                #pragma unroll
                for (int r = 0; r < 16; ++r) O[vt][r] *= rr[r];
        }

        // ---- P -> A-fragments (hi/lo) via cross-half exchange
        bf16x8 pah[2], pal[2];
        #pragma unroll
        for (int ks = 0; ks < 2; ++ks) {
            int b0 = 8 * ks;
            unsigned int wh[4], wl[4];
            #pragma unroll
            for (int i = 0; i < 4; ++i) {
                float a = sp[b0 + 2 * i], bb = sp[b0 + 2 * i + 1];
                __bf16 ha = (__bf16)a, hb = (__bf16)bb;
                BW wa, wb; wa.b = ha; wb.b = hb;
                wh[i] = (unsigned int)wa.s | ((unsigned int)wb.s << 16);
                float la = a - (float)ha, lb = bb - (float)hb;
                wl[i] = (unsigned int)bfbits(la) | ((unsigned int)bfbits(lb) << 16);
            }
            unsigned int s0h = __shfl_xor(wh[0], 32), s1h = __shfl_xor(wh[1], 32);
            unsigned int s2h = __shfl_xor(wh[2], 32), s3h = __shfl_xor(wh[3], 32);
            unsigned int s0l = __shfl_xor(wl[0], 32), s1l = __shfl_xor(wl[1], 32);
            unsigned int s2l = __shfl_xor(wl[2], 32), s3l = __shfl_xor(wl[3], 32);
            FW4 PH, PL;
            PH.u[0] = lh ? s2h : wh[0];
            PH.u[1] = lh ? s3h : wh[1];
            PH.u[2] = lh ? wh[2] : s0h;
            PH.u[3] = lh ? wh[3] : s1h;
            PL.u[0] = lh ? s2l : wl[0];
            PL.u[1] = lh ? s3l : wl[1];
            PL.u[2] = lh ? wl[2] : s0l;
            PL.u[3] = lh ? wl[3] : s1l;
            pah[ks] = PH.v; pal[ks] = PL.v;
        }

        // ---- O += P . V (3-term split)
        #pragma unroll
        for (int ks = 0; ks < 2; ++ks) {
            #pragma unroll
            for (int vt = 0; vt < 5; ++vt) {
                bf16x8 vh = *(const bf16x8*)&Vf[0][vt * 2 + ks][lane][0];
                bf16x8 vl = *(const bf16x8*)&Vf[1][vt * 2 + ks][lane][0];
                O[vt] = __builtin_amdgcn_mfma_f32_32x32x16_bf16(pah[ks], vh, O[vt], 0, 0, 0);
                O[vt] = __builtin_amdgcn_mfma_f32_32x32x16_bf16(pal[ks], vh, O[vt], 0, 0, 0);
                O[vt] = __builtin_amdgcn_mfma_f32_32x32x16_bf16(pah[ks], vl, O[vt], 0, 0, 0);
            }
        }
    }

    // ---- write partials
    float* P = part + (size_t)((b * HH + wid) * CT + c) * PSTRIDE;
    if (lane < 32) { P[lane] = m_run; P[JJ + lane] = l_run; }
    float* A = P + 2 * JJ;
    #pragma unroll
    for (int vt = 0; vt < 5; ++vt) {
        #pragma unroll
        for (int r = 0; r < 16; ++r) {
            int q = (r & 3) + 8 * (r >> 2) + (lh << 2);
            int v = vt * 32 + l31;
            if (v < VD) A[q * VD + v] = O[vt][r];
        }
    }
}

// -------------------------------------------- fused combine + output MLP ----
// Block = (b, j), 64 threads (1 wave). Chunk weights via wave shuffles,
// x[520] assembled in LDS, then 3-layer MLP.
template<int CT>
__global__ __launch_bounds__(64) void comb_mlp_kernel(
        const float* __restrict__ part,
        const float* __restrict__ W3, const float* __restrict__ b3,
        const float* __restrict__ W4, const float* __restrict__ b4,
        const float* __restrict__ W5, const float* __restrict__ b5,
        float* __restrict__ out) {
    int row = blockIdx.x;          // b*J + j
    int b = row >> 5;
    int j = row & 31;
    int t = threadIdx.x;
    __shared__ float w_s[HH][CT];
    __shared__ float x[HH * VD];
    __shared__ float h1[64];
    __shared__ float h2[32];

    if (t < HH * CT) {
        int h = t / CT, cc = t % CT;
        const float* P = part + (size_t)((b * HH + h) * CT + cc) * PSTRIDE;
        float m = P[j];
        float l = P[JJ + j];
        float mm = m;
        #pragma unroll
        for (int s = 1; s < CT; s <<= 1) mm = fmaxf(mm, __shfl_xor(mm, s));
        float e = __expf(m - mm);
        float L = l * e;
        #pragma unroll
        for (int s = 1; s < CT; s <<= 1) L += __shfl_xor(L, s);
        w_s[h][cc] = (L > 0.f) ? e / L : 0.f;
    }
    __syncthreads();

    for (int idx = t; idx < HH * VD; idx += 64) {
        int h = idx / VD, v = idx - h * VD;
        const float* A = part + (size_t)(b * HH + h) * CT * PSTRIDE + 2 * JJ + j * VD + v;
        float o = 0.f;
        #pragma unroll 4
        for (int cc = 0; cc < CT; ++cc) o += w_s[h][cc] * A[(size_t)cc * PSTRIDE];
        x[idx] = o;
    }
    __syncthreads();

    float a = b3[t];
    for (int i = 0; i < HH * VD; ++i) a += x[i] * W3[i * 64 + t];
    h1[t] = fmaxf(a, 0.f);
    __syncthreads();
    if (t < 32) {
        float a2 = b4[t];
        for (int i = 0; i < 64; ++i) a2 += h1[i] * W4[i * 32 + t];
        h2[t] = fmaxf(a2, 0.f);
    }
    __syncthreads();
    if (t == 0) {
        float a3 = b5[0];
        for (int i = 0; i < 32; ++i) a3 += h2[i] * W5[i];
        out[row] = a3;
    }
}

extern "C" void kernel_launch(void* const* d_in, const int* in_sizes, int n_in,
                              void* d_out, int out_size, void* d_ws, size_t ws_size,
                              hipStream_t stream) {
    const float* jq = (const float*)d_in[0];
    const float* Kg = (const float*)d_in[1];
    const float* Vg = (const float*)d_in[2];
    const int* mask = (const int*)d_in[3];
    const float* W1 = (const float*)d_in[4];
    const float* b1 = (const float*)d_in[5];
    const float* W2 = (const float*)d_in[6];
    const float* b2 = (const float*)d_in[7];
    const float* W3 = (const float*)d_in[8];
    const float* b3 = (const float*)d_in[9];
    const float* W4 = (const float*)d_in[10];
    const float* b4 = (const float*)d_in[11];
    const float* W5 = (const float*)d_in[12];
    const float* b5 = (const float*)d_in[13];
    float* out = (float*)d_out;

    float* ws = (float*)d_ws;
    float* qenc = ws;                                   // B*J*512 floats
    float* part = qenc + (size_t)BB * JJ * HH * KD;

    size_t need16 = ((size_t)BB * JJ * HH * KD + (size_t)BB * HH * 16 * PSTRIDE) * 4;

    enc_kernel<<<BB * JJ, 64, 0, stream>>>(jq, W1, b1, W2, b2, qenc);
    if (ws_size >= need16) {
        attn_kernel<16><<<BB * 16, 256, 0, stream>>>(Kg, Vg, mask, qenc, part);
        comb_mlp_kernel<16><<<BB * JJ, 64, 0, stream>>>(part, W3, b3, W4, b4, W5, b5, out);
    } else {
        attn_kernel<8><<<BB * 8, 256, 0, stream>>>(Kg, Vg, mask, qenc, part);
        comb_mlp_kernel<8><<<BB * JJ, 64, 0, stream>>>(part, W3, b3, W4, b4, W5, b5, out);
    }
}

// Round 5
// 246.752 us; speedup vs baseline: 1.3117x; 1.3117x over previous
//
#include <hip/hip_runtime.h>
#include <hip/hip_bf16.h>

#define BB 64
#define JJ 32
#define NN 4096
#define QD 130
#define KD 128
#define VD 130
#define HH 4
#define PSTRIDE (JJ + JJ + JJ * VD)   // 4224 floats per partial block

typedef __attribute__((ext_vector_type(8)))  __bf16 bf16x8;
typedef __attribute__((ext_vector_type(16))) float  f32x16;

union BW { __bf16 b; unsigned short s; };
union FW4 { unsigned int u[4]; bf16x8 v; };

__device__ inline unsigned short bfbits(float x) {
    BW w; w.b = (__bf16)x; return w.s;
}

// ---------------------------------------------------------------- encoder ---
__global__ __launch_bounds__(64) void enc_kernel(
        const float* __restrict__ jq,
        const float* __restrict__ W1, const float* __restrict__ b1,
        const float* __restrict__ W2, const float* __restrict__ b2,
        float* __restrict__ qenc) {
    int row = blockIdx.x;          // b*J + j
    int t = threadIdx.x;           // 0..63
    __shared__ float x[QD];
    __shared__ float h[64];
    for (int i = t; i < QD; i += 64) x[i] = jq[row * QD + i];
    __syncthreads();
    float acc = b1[t];
    for (int i = 0; i < QD; ++i) acc += x[i] * W1[i * 64 + t];
    h[t] = fmaxf(acc, 0.f);
    __syncthreads();
    for (int s = 0; s < 8; ++s) {
        int o = t + 64 * s;
        float a = b2[o];
        for (int i = 0; i < 64; ++i) a += h[i] * W2[i * 512 + o];
        qenc[row * 512 + o] = a;
    }
}

// -------------------------------------------------------------- attention ---
// Block = (b, chunk of NN/CT keys). 4 waves = 4 heads. Split-bf16 MFMA:
// S^T = mfma(K, Q), P->A-frags in-register, O += mfma(P, V).
// LDS holds fragment-linear bf16 hi/lo K and V tiles.
// NOTE: __launch_bounds__(256,2) — (256,4) forced VGPR 124->64 and caused
// ~260 MB/dispatch scratch spill traffic (round-4 regression). 4 blocks/CU
// still co-reside: VGPR 124<=128 and LDS 37.4KB*4 <= 160KB.
template<int CT>
__global__ __launch_bounds__(256, 2) void attn_kernel(
        const float* __restrict__ Kg, const float* __restrict__ Vg,
        const int* __restrict__ maskg, const float* __restrict__ qenc,
        float* __restrict__ part) {
    constexpr int NCH = NN / CT;
    constexpr int TIL = NCH / 32;
    int blk = blockIdx.x;
    int c = blk & (CT - 1);
    int b = blk / CT;
    int tid = threadIdx.x;
    int wid = tid >> 6;            // head
    int lane = tid & 63;
    int l31 = lane & 31;
    int lh = lane >> 5;            // half-wave index

    // fragment-linear LDS: [plane hi/lo][kstep][lane][8 bf16]
    __shared__ __align__(16) __bf16 Kf[2][8][64][8];     // 16 KB
    __shared__ __align__(16) __bf16 Vf[2][10][64][8];    // 20 KB  (g = vt*2+ks)
    __shared__ float r_lds[4][32];

    // ---- Q B-fragments in registers (hi/lo), 8 k-steps
    bf16x8 qh[8], ql[8];
    {
        const float* qrow = qenc + (size_t)(b * JJ + l31) * 512 + wid * KD + lh * 8;
        #pragma unroll
        for (int kst = 0; kst < 8; ++kst) {
            float f[8];
            *(float4*)&f[0] = *(const float4*)(qrow + kst * 16);
            *(float4*)&f[4] = *(const float4*)(qrow + kst * 16 + 4);
            FW4 H, L;
            #pragma unroll
            for (int i = 0; i < 4; ++i) {
                __bf16 h0 = (__bf16)f[2 * i], h1 = (__bf16)f[2 * i + 1];
                BW w0, w1; w0.b = h0; w1.b = h1;
                H.u[i] = (unsigned int)w0.s | ((unsigned int)w1.s << 16);
                float r0 = f[2 * i] - (float)h0, r1 = f[2 * i + 1] - (float)h1;
                L.u[i] = (unsigned int)bfbits(r0) | ((unsigned int)bfbits(r1) << 16);
            }
            qh[kst] = H.v; ql[kst] = L.v;
        }
    }

    f32x16 O[5];
    #pragma unroll
    for (int vt = 0; vt < 5; ++vt)
        #pragma unroll
        for (int r = 0; r < 16; ++r) O[vt][r] = 0.f;
    float m_run = -1e30f, l_run = 0.f;

    const float* Kb = Kg + (size_t)b * NN * KD;
    const float* Vb = Vg + (size_t)b * NN * VD;
    const int*   Mb = maskg + b * NN;

    for (int t = 0; t < TIL; ++t) {
        int n0 = c * NCH + t * 32;
        __syncthreads();
        // ---- stage K fragments (512 positions, 2 per thread)
        #pragma unroll
        for (int pp = 0; pp < 2; ++pp) {
            int p = tid + pp * 256;
            int kst = p >> 6, sl = p & 63;
            const float* src = Kb + (size_t)(n0 + (sl & 31)) * KD + kst * 16 + (sl >> 5) * 8;
            float f[8];
            *(float4*)&f[0] = *(const float4*)(src);
            *(float4*)&f[4] = *(const float4*)(src + 4);
            FW4 H, L;
            #pragma unroll
            for (int i = 0; i < 4; ++i) {
                __bf16 h0 = (__bf16)f[2 * i], h1 = (__bf16)f[2 * i + 1];
                BW w0, w1; w0.b = h0; w1.b = h1;
                H.u[i] = (unsigned int)w0.s | ((unsigned int)w1.s << 16);
                float r0 = f[2 * i] - (float)h0, r1 = f[2 * i + 1] - (float)h1;
                L.u[i] = (unsigned int)bfbits(r0) | ((unsigned int)bfbits(r1) << 16);
            }
            *(bf16x8*)&Kf[0][kst][sl][0] = H.v;
            *(bf16x8*)&Kf[1][kst][sl][0] = L.v;
        }
        // ---- stage V fragments (640 positions)
        for (int p = tid; p < 640; p += 256) {
            int g = p >> 6, sl = p & 63;
            int vt = g >> 1, ks = g & 1;
            int v = vt * 32 + (sl & 31);
            int nr = n0 + ks * 16 + (sl >> 5) * 8;
            float f[8];
            #pragma unroll
            for (int j = 0; j < 8; ++j)
                f[j] = (v < VD) ? Vb[(size_t)(nr + j) * VD + v] : 0.f;
            FW4 H, L;
            #pragma unroll
            for (int i = 0; i < 4; ++i) {
                __bf16 h0 = (__bf16)f[2 * i], h1 = (__bf16)f[2 * i + 1];
                BW w0, w1; w0.b = h0; w1.b = h1;
                H.u[i] = (unsigned int)w0.s | ((unsigned int)w1.s << 16);
                float r0 = f[2 * i] - (float)h0, r1 = f[2 * i + 1] - (float)h1;
                L.u[i] = (unsigned int)bfbits(r0) | ((unsigned int)bfbits(r1) << 16);
            }
            *(bf16x8*)&Vf[0][g][sl][0] = H.v;
            *(bf16x8*)&Vf[1][g][sl][0] = L.v;
        }
        __syncthreads();

        // ---- mask word for this 32-key tile
        int mv = Mb[n0 + l31];
        unsigned int mword = (unsigned int)__ballot(mv != 0);

        // ---- S^T = K . Q  (3-term split)
        f32x16 S;
        #pragma unroll
        for (int r = 0; r < 16; ++r) S[r] = 0.f;
        #pragma unroll
        for (int kst = 0; kst < 8; ++kst) {
            bf16x8 kh = *(const bf16x8*)&Kf[0][kst][lane][0];
            bf16x8 kl = *(const bf16x8*)&Kf[1][kst][lane][0];
            S = __builtin_amdgcn_mfma_f32_32x32x16_bf16(kh, qh[kst], S, 0, 0, 0);
            S = __builtin_amdgcn_mfma_f32_32x32x16_bf16(kh, ql[kst], S, 0, 0, 0);
            S = __builtin_amdgcn_mfma_f32_32x32x16_bf16(kl, qh[kst], S, 0, 0, 0);
        }

        // ---- mask + scale, online softmax (per-lane column q = lane&31)
        const float sc = 0.08838834764831845f;
        float sp[16];
        float rm = -1e30f;
        #pragma unroll
        for (int r = 0; r < 16; ++r) {
            int key = (r & 3) + 8 * (r >> 2) + (lh << 2);
            float s = ((mword >> key) & 1u) ? -1e30f : S[r] * sc;
            sp[r] = s;
            rm = fmaxf(rm, s);
        }
        rm = fmaxf(rm, __shfl_xor(rm, 32));
        float mn = fmaxf(m_run, rm);
        float rs = __expf(m_run - mn);
        m_run = mn;
        float ps = 0.f;
        #pragma unroll
        for (int r = 0; r < 16; ++r) {
            float p = __expf(sp[r] - mn);
            sp[r] = p;
            ps += p;
        }
        ps += __shfl_xor(ps, 32);
        l_run = l_run * rs + ps;

        if (lane < 32) r_lds[wid][lane] = rs;
        if (!__all(rs == 1.0f)) {
            float rr[16];
            #pragma unroll
            for (int r = 0; r < 16; ++r)
                rr[r] = r_lds[wid][(r & 3) + 8 * (r >> 2) + (lh << 2)];
            #pragma unroll
            for (int vt = 0; vt < 5; ++vt)
                #pragma unroll
                for (int r = 0; r < 16; ++r) O[vt][r] *= rr[r];
        }

        // ---- P -> A-fragments (hi/lo) via cross-half exchange
        bf16x8 pah[2], pal[2];
        #pragma unroll
        for (int ks = 0; ks < 2; ++ks) {
            int b0 = 8 * ks;
            unsigned int wh[4], wl[4];
            #pragma unroll
            for (int i = 0; i < 4; ++i) {
                float a = sp[b0 + 2 * i], bb = sp[b0 + 2 * i + 1];
                __bf16 ha = (__bf16)a, hb = (__bf16)bb;
                BW wa, wb; wa.b = ha; wb.b = hb;
                wh[i] = (unsigned int)wa.s | ((unsigned int)wb.s << 16);
                float la = a - (float)ha, lb = bb - (float)hb;
                wl[i] = (unsigned int)bfbits(la) | ((unsigned int)bfbits(lb) << 16);
            }
            unsigned int s0h = __shfl_xor(wh[0], 32), s1h = __shfl_xor(wh[1], 32);
            unsigned int s2h = __shfl_xor(wh[2], 32), s3h = __shfl_xor(wh[3], 32);
            unsigned int s0l = __shfl_xor(wl[0], 32), s1l = __shfl_xor(wl[1], 32);
            unsigned int s2l = __shfl_xor(wl[2], 32), s3l = __shfl_xor(wl[3], 32);
            FW4 PH, PL;
            PH.u[0] = lh ? s2h : wh[0];
            PH.u[1] = lh ? s3h : wh[1];
            PH.u[2] = lh ? wh[2] : s0h;
            PH.u[3] = lh ? wh[3] : s1h;
            PL.u[0] = lh ? s2l : wl[0];
            PL.u[1] = lh ? s3l : wl[1];
            PL.u[2] = lh ? wl[2] : s0l;
            PL.u[3] = lh ? wl[3] : s1l;
            pah[ks] = PH.v; pal[ks] = PL.v;
        }

        // ---- O += P . V (3-term split)
        #pragma unroll
        for (int ks = 0; ks < 2; ++ks) {
            #pragma unroll
            for (int vt = 0; vt < 5; ++vt) {
                bf16x8 vh = *(const bf16x8*)&Vf[0][vt * 2 + ks][lane][0];
                bf16x8 vl = *(const bf16x8*)&Vf[1][vt * 2 + ks][lane][0];
                O[vt] = __builtin_amdgcn_mfma_f32_32x32x16_bf16(pah[ks], vh, O[vt], 0, 0, 0);
                O[vt] = __builtin_amdgcn_mfma_f32_32x32x16_bf16(pal[ks], vh, O[vt], 0, 0, 0);
                O[vt] = __builtin_amdgcn_mfma_f32_32x32x16_bf16(pah[ks], vl, O[vt], 0, 0, 0);
            }
        }
    }

    // ---- write partials
    float* P = part + (size_t)((b * HH + wid) * CT + c) * PSTRIDE;
    if (lane < 32) { P[lane] = m_run; P[JJ + lane] = l_run; }
    float* A = P + 2 * JJ;
    #pragma unroll
    for (int vt = 0; vt < 5; ++vt) {
        #pragma unroll
        for (int r = 0; r < 16; ++r) {
            int q = (r & 3) + 8 * (r >> 2) + (lh << 2);
            int v = vt * 32 + l31;
            if (v < VD) A[q * VD + v] = O[vt][r];
        }
    }
}

// -------------------------------------------- fused combine + output MLP ----
// Block = (b, j), 64 threads (1 wave). Chunk weights via wave shuffles,
// x[520] assembled in LDS, then 3-layer MLP.
template<int CT>
__global__ __launch_bounds__(64) void comb_mlp_kernel(
        const float* __restrict__ part,
        const float* __restrict__ W3, const float* __restrict__ b3,
        const float* __restrict__ W4, const float* __restrict__ b4,
        const float* __restrict__ W5, const float* __restrict__ b5,
        float* __restrict__ out) {
    int row = blockIdx.x;          // b*J + j
    int b = row >> 5;
    int j = row & 31;
    int t = threadIdx.x;
    __shared__ float w_s[HH][CT];
    __shared__ float x[HH * VD];
    __shared__ float h1[64];
    __shared__ float h2[32];

    if (t < HH * CT) {
        int h = t / CT, cc = t % CT;
        const float* P = part + (size_t)((b * HH + h) * CT + cc) * PSTRIDE;
        float m = P[j];
        float l = P[JJ + j];
        float mm = m;
        #pragma unroll
        for (int s = 1; s < CT; s <<= 1) mm = fmaxf(mm, __shfl_xor(mm, s));
        float e = __expf(m - mm);
        float L = l * e;
        #pragma unroll
        for (int s = 1; s < CT; s <<= 1) L += __shfl_xor(L, s);
        w_s[h][cc] = (L > 0.f) ? e / L : 0.f;
    }
    __syncthreads();

    for (int idx = t; idx < HH * VD; idx += 64) {
        int h = idx / VD, v = idx - h * VD;
        const float* A = part + (size_t)(b * HH + h) * CT * PSTRIDE + 2 * JJ + j * VD + v;
        float o = 0.f;
        #pragma unroll 4
        for (int cc = 0; cc < CT; ++cc) o += w_s[h][cc] * A[(size_t)cc * PSTRIDE];
        x[idx] = o;
    }
    __syncthreads();

    float a = b3[t];
    for (int i = 0; i < HH * VD; ++i) a += x[i] * W3[i * 64 + t];
    h1[t] = fmaxf(a, 0.f);
    __syncthreads();
    if (t < 32) {
        float a2 = b4[t];
        for (int i = 0; i < 64; ++i) a2 += h1[i] * W4[i * 32 + t];
        h2[t] = fmaxf(a2, 0.f);
    }
    __syncthreads();
    if (t == 0) {
        float a3 = b5[0];
        for (int i = 0; i < 32; ++i) a3 += h2[i] * W5[i];
        out[row] = a3;
    }
}

extern "C" void kernel_launch(void* const* d_in, const int* in_sizes, int n_in,
                              void* d_out, int out_size, void* d_ws, size_t ws_size,
                              hipStream_t stream) {
    const float* jq = (const float*)d_in[0];
    const float* Kg = (const float*)d_in[1];
    const float* Vg = (const float*)d_in[2];
    const int* mask = (const int*)d_in[3];
    const float* W1 = (const float*)d_in[4];
    const float* b1 = (const float*)d_in[5];
    const float* W2 = (const float*)d_in[6];
    const float* b2 = (const float*)d_in[7];
    const float* W3 = (const float*)d_in[8];
    const float* b3 = (const float*)d_in[9];
    const float* W4 = (const float*)d_in[10];
    const float* b4 = (const float*)d_in[11];
    const float* W5 = (const float*)d_in[12];
    const float* b5 = (const float*)d_in[13];
    float* out = (float*)d_out;

    float* ws = (float*)d_ws;
    float* qenc = ws;                                   // B*J*512 floats
    float* part = qenc + (size_t)BB * JJ * HH * KD;

    size_t need16 = ((size_t)BB * JJ * HH * KD + (size_t)BB * HH * 16 * PSTRIDE) * 4;

    enc_kernel<<<BB * JJ, 64, 0, stream>>>(jq, W1, b1, W2, b2, qenc);
    if (ws_size >= need16) {
        attn_kernel<16><<<BB * 16, 256, 0, stream>>>(Kg, Vg, mask, qenc, part);
        comb_mlp_kernel<16><<<BB * JJ, 64, 0, stream>>>(part, W3, b3, W4, b4, W5, b5, out);
    } else {
        attn_kernel<8><<<BB * 8, 256, 0, stream>>>(Kg, Vg, mask, qenc, part);
        comb_mlp_kernel<8><<<BB * JJ, 64, 0, stream>>>(part, W3, b3, W4, b4, W5, b5, out);
    }
}

// Round 6
// 211.788 us; speedup vs baseline: 1.5283x; 1.1651x over previous
//
#include <hip/hip_runtime.h>
#include <hip/hip_bf16.h>

#define BB 64
#define JJ 32
#define NN 4096
#define QD 130
#define KD 128
#define VD 130
#define HH 4
#define PSTRIDE (JJ + JJ + JJ * VD)   // 4224 floats per partial block

typedef __attribute__((ext_vector_type(8)))  __bf16 bf16x8;
typedef __attribute__((ext_vector_type(16))) float  f32x16;

union BW { __bf16 b; unsigned short s; };
union FW4 { unsigned int u[4]; bf16x8 v; };

__device__ inline unsigned short bfbits(float x) {
    BW w; w.b = (__bf16)x; return w.s;
}

// split one 8-float vector into hi/lo bf16x8 planes
__device__ inline void cvt8(const float* f, bf16x8* dh, bf16x8* dl) {
    FW4 H, L;
    #pragma unroll
    for (int i = 0; i < 4; ++i) {
        __bf16 h0 = (__bf16)f[2 * i], h1 = (__bf16)f[2 * i + 1];
        BW w0, w1; w0.b = h0; w1.b = h1;
        H.u[i] = (unsigned int)w0.s | ((unsigned int)w1.s << 16);
        float r0 = f[2 * i] - (float)h0, r1 = f[2 * i + 1] - (float)h1;
        L.u[i] = (unsigned int)bfbits(r0) | ((unsigned int)bfbits(r1) << 16);
    }
    *dh = H.v; *dl = L.v;
}

// ---------------------------------------------------------------- encoder ---
__global__ __launch_bounds__(64) void enc_kernel(
        const float* __restrict__ jq,
        const float* __restrict__ W1, const float* __restrict__ b1,
        const float* __restrict__ W2, const float* __restrict__ b2,
        float* __restrict__ qenc) {
    int row = blockIdx.x;          // b*J + j
    int t = threadIdx.x;           // 0..63
    __shared__ float x[QD];
    __shared__ float h[64];
    for (int i = t; i < QD; i += 64) x[i] = jq[row * QD + i];
    __syncthreads();
    float acc = b1[t];
    for (int i = 0; i < QD; ++i) acc += x[i] * W1[i * 64 + t];
    h[t] = fmaxf(acc, 0.f);
    __syncthreads();
    for (int s = 0; s < 8; ++s) {
        int o = t + 64 * s;
        float a = b2[o];
        for (int i = 0; i < 64; ++i) a += h[i] * W2[i * 512 + o];
        qenc[row * 512 + o] = a;
    }
}

// -------------------------------------------------------------- attention ---
// Block = (b, chunk of NN/CT keys). 4 waves = 4 heads. Split-bf16 MFMA.
// T14 double-buffer: tile t+1's global loads are issued BEFORE tile t's
// compute and converted/written to the idle LDS buffer after it; one
// barrier per tile. V-cols 128/129 handled via exact fp32 VALU tail
// (drops the mostly-empty 5th V MFMA tile; O: 80->64 regs).
template<int CT>
__global__ __launch_bounds__(256, 2) void attn_kernel(
        const float* __restrict__ Kg, const float* __restrict__ Vg,
        const int* __restrict__ maskg, const float* __restrict__ qenc,
        float* __restrict__ part) {
    constexpr int NCH = NN / CT;
    constexpr int TIL = NCH / 32;
    int blk = blockIdx.x;
    int c = blk & (CT - 1);
    int b = blk / CT;
    int tid = threadIdx.x;
    int wid = tid >> 6;            // head
    int lane = tid & 63;
    int l31 = lane & 31;
    int lh = lane >> 5;            // half-wave index

    // [buf][plane hi/lo][kstep|group][lane][8 bf16]
    __shared__ __align__(16) __bf16 Kf[2][2][8][64][8];  // 32 KB
    __shared__ __align__(16) __bf16 Vf[2][2][8][64][8];  // 32 KB
    __shared__ float2 Vt_s[2][32];                       // fp32 V tail cols 128..129
    __shared__ int    msk_s[2][32];
    __shared__ float  r_lds[4][32];

    // per-thread staging geometry (constant across tiles)
    const int sl = tid & 63;
    const int srow = sl & 31;
    const int scol8 = (sl >> 5) * 8;
    const int kstA = tid >> 6, kstB = kstA + 4;     // K k-steps
    const int gA = tid >> 6,   gB = gA + 4;         // V groups (vt = g>>1, ks = g&1)
    const int vAcol = (gA >> 1) * 32 + srow;
    const int vArow = (gA & 1) * 16 + scol8;
    const int vBcol = (gB >> 1) * 32 + srow;
    const int vBrow = (gB & 1) * 16 + scol8;

    const float* Kb = Kg + (size_t)b * NN * KD;
    const float* Vb = Vg + (size_t)b * NN * VD;
    const int*   Mb = maskg + b * NN;

    // in-flight load bundle (lives across one compute phase)
    float kA[8], kB[8], vA[8], vB[8];
    float2 vtR = {0.f, 0.f};
    int mkR = 0;

    #define ISSUE_LOADS(T) {                                                   \
        int n0_ = c * NCH + (T) * 32;                                          \
        const float* ka_ = Kb + (size_t)(n0_ + srow) * KD + kstA * 16 + scol8; \
        *(float4*)&kA[0] = *(const float4*)(ka_);                              \
        *(float4*)&kA[4] = *(const float4*)(ka_ + 4);                          \
        const float* kb_ = Kb + (size_t)(n0_ + srow) * KD + kstB * 16 + scol8; \
        *(float4*)&kB[0] = *(const float4*)(kb_);                              \
        *(float4*)&kB[4] = *(const float4*)(kb_ + 4);                          \
        _Pragma("unroll")                                                      \
        for (int j = 0; j < 8; ++j)                                            \
            vA[j] = Vb[(size_t)(n0_ + vArow + j) * VD + vAcol];                \
        _Pragma("unroll")                                                      \
        for (int j = 0; j < 8; ++j)                                            \
            vB[j] = Vb[(size_t)(n0_ + vBrow + j) * VD + vBcol];                \
        if (tid < 32) {                                                        \
            vtR = *(const float2*)(Vb + (size_t)(n0_ + tid) * VD + 128);       \
            mkR = Mb[n0_ + tid];                                               \
        }                                                                      \
    }

    #define CONVERT_WRITE(BUF) {                                               \
        cvt8(kA, (bf16x8*)&Kf[BUF][0][kstA][sl][0], (bf16x8*)&Kf[BUF][1][kstA][sl][0]); \
        cvt8(kB, (bf16x8*)&Kf[BUF][0][kstB][sl][0], (bf16x8*)&Kf[BUF][1][kstB][sl][0]); \
        cvt8(vA, (bf16x8*)&Vf[BUF][0][gA][sl][0],   (bf16x8*)&Vf[BUF][1][gA][sl][0]);   \
        cvt8(vB, (bf16x8*)&Vf[BUF][0][gB][sl][0],   (bf16x8*)&Vf[BUF][1][gB][sl][0]);   \
        if (tid < 32) { Vt_s[BUF][tid] = vtR; msk_s[BUF][tid] = mkR; }         \
    }

    ISSUE_LOADS(0);

    // ---- Q B-fragments in registers (hi/lo) — overlaps tile-0 load latency
    bf16x8 qh[8], ql[8];
    {
        const float* qrow = qenc + (size_t)(b * JJ + l31) * 512 + wid * KD + lh * 8;
        #pragma unroll
        for (int kst = 0; kst < 8; ++kst) {
            float f[8];
            *(float4*)&f[0] = *(const float4*)(qrow + kst * 16);
            *(float4*)&f[4] = *(const float4*)(qrow + kst * 16 + 4);
            cvt8(f, &qh[kst], &ql[kst]);
        }
    }

    f32x16 O[4];
    #pragma unroll
    for (int vt = 0; vt < 4; ++vt)
        #pragma unroll
        for (int r = 0; r < 16; ++r) O[vt][r] = 0.f;
    float acct0 = 0.f, acct1 = 0.f;    // fp32 tail accum (per-lane q = l31)
    float m_run = -1e30f, l_run = 0.f;

    CONVERT_WRITE(0);
    ISSUE_LOADS(1);
    __syncthreads();

    for (int t = 0; t < TIL; ++t) {
        int cur = t & 1;

        // ---- mask word for this 32-key tile
        int mv = msk_s[cur][l31];
        unsigned int mword = (unsigned int)__ballot(mv != 0);

        // ---- S^T = K . Q  (3-term split)
        f32x16 S;
        #pragma unroll
        for (int r = 0; r < 16; ++r) S[r] = 0.f;
        #pragma unroll
        for (int kst = 0; kst < 8; ++kst) {
            bf16x8 kh = *(const bf16x8*)&Kf[cur][0][kst][lane][0];
            bf16x8 kl = *(const bf16x8*)&Kf[cur][1][kst][lane][0];
            S = __builtin_amdgcn_mfma_f32_32x32x16_bf16(kh, qh[kst], S, 0, 0, 0);
            S = __builtin_amdgcn_mfma_f32_32x32x16_bf16(kh, ql[kst], S, 0, 0, 0);
            S = __builtin_amdgcn_mfma_f32_32x32x16_bf16(kl, qh[kst], S, 0, 0, 0);
        }

        // ---- mask + scale, online softmax (per-lane column q = lane&31)
        const float sc = 0.08838834764831845f;
        float sp[16];
        float rm = -1e30f;
        #pragma unroll
        for (int r = 0; r < 16; ++r) {
            int key = (r & 3) + 8 * (r >> 2) + (lh << 2);
            float s = ((mword >> key) & 1u) ? -1e30f : S[r] * sc;
            sp[r] = s;
            rm = fmaxf(rm, s);
        }
        rm = fmaxf(rm, __shfl_xor(rm, 32));
        float mn = fmaxf(m_run, rm);
        float rs = __expf(m_run - mn);
        m_run = mn;
        float ps = 0.f;
        #pragma unroll
        for (int r = 0; r < 16; ++r) {
            float p = __expf(sp[r] - mn);
            sp[r] = p;
            ps += p;
        }
        ps += __shfl_xor(ps, 32);
        l_run = l_run * rs + ps;

        if (lane < 32) r_lds[wid][lane] = rs;
        if (!__all(rs == 1.0f)) {
            acct0 *= rs;               // tail is q-mapped: use per-lane rs
            acct1 *= rs;
            float rr[16];
            #pragma unroll
            for (int r = 0; r < 16; ++r)
                rr[r] = r_lds[wid][(r & 3) + 8 * (r >> 2) + (lh << 2)];
            #pragma unroll
            for (int vt = 0; vt < 4; ++vt)
                #pragma unroll
                for (int r = 0; r < 16; ++r) O[vt][r] *= rr[r];
        }

        // ---- fp32 tail: out[q][128|129] += sum_n p[q][n] * V[n][128|129]
        #pragma unroll
        for (int r = 0; r < 16; ++r) {
            int key = (r & 3) + 8 * (r >> 2) + (lh << 2);
            float2 tv = Vt_s[cur][key];
            acct0 += sp[r] * tv.x;
            acct1 += sp[r] * tv.y;
        }

        // ---- P -> A-fragments (hi/lo) via cross-half exchange
        bf16x8 pah[2], pal[2];
        #pragma unroll
        for (int ks = 0; ks < 2; ++ks) {
            int b0 = 8 * ks;
            unsigned int wh[4], wl[4];
            #pragma unroll
            for (int i = 0; i < 4; ++i) {
                float a = sp[b0 + 2 * i], bb = sp[b0 + 2 * i + 1];
                __bf16 ha = (__bf16)a, hb = (__bf16)bb;
                BW wa, wb; wa.b = ha; wb.b = hb;
                wh[i] = (unsigned int)wa.s | ((unsigned int)wb.s << 16);
                float la = a - (float)ha, lb = bb - (float)hb;
                wl[i] = (unsigned int)bfbits(la) | ((unsigned int)bfbits(lb) << 16);
            }
            unsigned int s0h = __shfl_xor(wh[0], 32), s1h = __shfl_xor(wh[1], 32);
            unsigned int s2h = __shfl_xor(wh[2], 32), s3h = __shfl_xor(wh[3], 32);
            unsigned int s0l = __shfl_xor(wl[0], 32), s1l = __shfl_xor(wl[1], 32);
            unsigned int s2l = __shfl_xor(wl[2], 32), s3l = __shfl_xor(wl[3], 32);
            FW4 PH, PL;
            PH.u[0] = lh ? s2h : wh[0];
            PH.u[1] = lh ? s3h : wh[1];
            PH.u[2] = lh ? wh[2] : s0h;
            PH.u[3] = lh ? wh[3] : s1h;
            PL.u[0] = lh ? s2l : wl[0];
            PL.u[1] = lh ? s3l : wl[1];
            PL.u[2] = lh ? wl[2] : s0l;
            PL.u[3] = lh ? wl[3] : s1l;
            pah[ks] = PH.v; pal[ks] = PL.v;
        }

        // ---- O += P . V (3-term split, 4 V-tiles)
        #pragma unroll
        for (int ks = 0; ks < 2; ++ks) {
            #pragma unroll
            for (int vt = 0; vt < 4; ++vt) {
                bf16x8 vh = *(const bf16x8*)&Vf[cur][0][vt * 2 + ks][lane][0];
                bf16x8 vl = *(const bf16x8*)&Vf[cur][1][vt * 2 + ks][lane][0];
                O[vt] = __builtin_amdgcn_mfma_f32_32x32x16_bf16(pah[ks], vh, O[vt], 0, 0, 0);
                O[vt] = __builtin_amdgcn_mfma_f32_32x32x16_bf16(pal[ks], vh, O[vt], 0, 0, 0);
                O[vt] = __builtin_amdgcn_mfma_f32_32x32x16_bf16(pah[ks], vl, O[vt], 0, 0, 0);
            }
        }

        // ---- write next tile into the idle buffer; refill the bundle
        if (t + 1 < TIL) {
            CONVERT_WRITE((t + 1) & 1);
            if (t + 2 < TIL) ISSUE_LOADS(t + 2);
        }
        __syncthreads();
    }

    // ---- write partials
    float* P = part + (size_t)((b * HH + wid) * CT + c) * PSTRIDE;
    if (lane < 32) { P[lane] = m_run; P[JJ + lane] = l_run; }
    float* A = P + 2 * JJ;
    #pragma unroll
    for (int vt = 0; vt < 4; ++vt) {
        #pragma unroll
        for (int r = 0; r < 16; ++r) {
            int q = (r & 3) + 8 * (r >> 2) + (lh << 2);
            A[q * VD + vt * 32 + l31] = O[vt][r];
        }
    }
    float t0 = acct0 + __shfl_xor(acct0, 32);
    float t1 = acct1 + __shfl_xor(acct1, 32);
    if (lh == 0) {
        A[l31 * VD + 128] = t0;
        A[l31 * VD + 129] = t1;
    }
    #undef ISSUE_LOADS
    #undef CONVERT_WRITE
}

// -------------------------------------------- fused combine + output MLP ----
template<int CT>
__global__ __launch_bounds__(64) void comb_mlp_kernel(
        const float* __restrict__ part,
        const float* __restrict__ W3, const float* __restrict__ b3,
        const float* __restrict__ W4, const float* __restrict__ b4,
        const float* __restrict__ W5, const float* __restrict__ b5,
        float* __restrict__ out) {
    int row = blockIdx.x;          // b*J + j
    int b = row >> 5;
    int j = row & 31;
    int t = threadIdx.x;
    __shared__ float w_s[HH][CT];
    __shared__ float x[HH * VD];
    __shared__ float h1[64];
    __shared__ float h2[32];

    if (t < HH * CT) {
        int h = t / CT, cc = t % CT;
        const float* P = part + (size_t)((b * HH + h) * CT + cc) * PSTRIDE;
        float m = P[j];
        float l = P[JJ + j];
        float mm = m;
        #pragma unroll
        for (int s = 1; s < CT; s <<= 1) mm = fmaxf(mm, __shfl_xor(mm, s));
        float e = __expf(m - mm);
        float L = l * e;
        #pragma unroll
        for (int s = 1; s < CT; s <<= 1) L += __shfl_xor(L, s);
        w_s[h][cc] = (L > 0.f) ? e / L : 0.f;
    }
    __syncthreads();

    for (int idx = t; idx < HH * VD; idx += 64) {
        int h = idx / VD, v = idx - h * VD;
        const float* A = part + (size_t)(b * HH + h) * CT * PSTRIDE + 2 * JJ + j * VD + v;
        float o = 0.f;
        #pragma unroll 4
        for (int cc = 0; cc < CT; ++cc) o += w_s[h][cc] * A[(size_t)cc * PSTRIDE];
        x[idx] = o;
    }
    __syncthreads();

    float a = b3[t];
    #pragma unroll 8
    for (int i = 0; i < HH * VD; ++i) a += x[i] * W3[i * 64 + t];
    h1[t] = fmaxf(a, 0.f);
    __syncthreads();
    if (t < 32) {
        float a2 = b4[t];
        for (int i = 0; i < 64; ++i) a2 += h1[i] * W4[i * 32 + t];
        h2[t] = fmaxf(a2, 0.f);
    }
    __syncthreads();
    if (t == 0) {
        float a3 = b5[0];
        for (int i = 0; i < 32; ++i) a3 += h2[i] * W5[i];
        out[row] = a3;
    }
}

extern "C" void kernel_launch(void* const* d_in, const int* in_sizes, int n_in,
                              void* d_out, int out_size, void* d_ws, size_t ws_size,
                              hipStream_t stream) {
    const float* jq = (const float*)d_in[0];
    const float* Kg = (const float*)d_in[1];
    const float* Vg = (const float*)d_in[2];
    const int* mask = (const int*)d_in[3];
    const float* W1 = (const float*)d_in[4];
    const float* b1 = (const float*)d_in[5];
    const float* W2 = (const float*)d_in[6];
    const float* b2 = (const float*)d_in[7];
    const float* W3 = (const float*)d_in[8];
    const float* b3 = (const float*)d_in[9];
    const float* W4 = (const float*)d_in[10];
    const float* b4 = (const float*)d_in[11];
    const float* W5 = (const float*)d_in[12];
    const float* b5 = (const float*)d_in[13];
    float* out = (float*)d_out;

    float* ws = (float*)d_ws;
    float* qenc = ws;                                   // B*J*512 floats
    float* part = qenc + (size_t)BB * JJ * HH * KD;

    size_t need16 = ((size_t)BB * JJ * HH * KD + (size_t)BB * HH * 16 * PSTRIDE) * 4;

    enc_kernel<<<BB * JJ, 64, 0, stream>>>(jq, W1, b1, W2, b2, qenc);
    if (ws_size >= need16) {
        attn_kernel<16><<<BB * 16, 256, 0, stream>>>(Kg, Vg, mask, qenc, part);
        comb_mlp_kernel<16><<<BB * JJ, 64, 0, stream>>>(part, W3, b3, W4, b4, W5, b5, out);
    } else {
        attn_kernel<8><<<BB * 8, 256, 0, stream>>>(Kg, Vg, mask, qenc, part);
        comb_mlp_kernel<8><<<BB * JJ, 64, 0, stream>>>(part, W3, b3, W4, b4, W5, b5, out);
    }
}

// Round 7
// 172.570 us; speedup vs baseline: 1.8756x; 1.2273x over previous
//
#include <hip/hip_runtime.h>
#include <hip/hip_bf16.h>

#define BB 64
#define JJ 32
#define NN 4096
#define QD 130
#define KD 128
#define VD 130
#define HH 4
#define CT 8
#define NCH (NN / CT)                 // 512
#define TIL (NCH / 32)                // 16
#define PSTRIDE (JJ + JJ + JJ * VD)   // 4224 floats per partial block

typedef __attribute__((ext_vector_type(8)))  __bf16 bf16x8;
typedef __attribute__((ext_vector_type(16))) float  f32x16;

union FW4 { unsigned int u[4]; bf16x8 v; };

#define SEL_HI 0x07060302u

__device__ __forceinline__ unsigned int packhi(float f0, float f1) {
    // {hi16(f1), hi16(f0)} in one v_perm_b32
    return __builtin_amdgcn_perm(__float_as_uint(f1), __float_as_uint(f0), SEL_HI);
}
__device__ __forceinline__ float truncbf(float f) {
    return __uint_as_float(__float_as_uint(f) & 0xFFFF0000u);
}
// truncation split: 8 floats -> hi/lo bf16x8 planes (f = h + l + O(2^-17))
__device__ __forceinline__ void split8(float4 a, float4 b, bf16x8* h, bf16x8* l) {
    FW4 H, L;
    H.u[0] = packhi(a.x, a.y);
    H.u[1] = packhi(a.z, a.w);
    H.u[2] = packhi(b.x, b.y);
    H.u[3] = packhi(b.z, b.w);
    L.u[0] = packhi(a.x - truncbf(a.x), a.y - truncbf(a.y));
    L.u[1] = packhi(a.z - truncbf(a.z), a.w - truncbf(a.w));
    L.u[2] = packhi(b.x - truncbf(b.x), b.y - truncbf(b.y));
    L.u[3] = packhi(b.z - truncbf(b.z), b.w - truncbf(b.w));
    *h = H.v; *l = L.v;
}

__device__ __forceinline__ void cp16(float* lds, const float* g) {
    __builtin_amdgcn_global_load_lds(
        (const __attribute__((address_space(1))) unsigned int*)g,
        (__attribute__((address_space(3))) unsigned int*)lds, 16, 0, 0);
}
__device__ __forceinline__ void cp4(float* lds, const float* g) {
    __builtin_amdgcn_global_load_lds(
        (const __attribute__((address_space(1))) unsigned int*)g,
        (__attribute__((address_space(3))) unsigned int*)lds, 4, 0, 0);
}

// ---------------------------------------------------------------- encoder ---
__global__ __launch_bounds__(64) void enc_kernel(
        const float* __restrict__ jq,
        const float* __restrict__ W1, const float* __restrict__ b1,
        const float* __restrict__ W2, const float* __restrict__ b2,
        float* __restrict__ qenc) {
    int row = blockIdx.x;          // b*J + j
    int t = threadIdx.x;           // 0..63
    __shared__ float x[QD];
    __shared__ float h[64];
    for (int i = t; i < QD; i += 64) x[i] = jq[row * QD + i];
    __syncthreads();
    float acc = b1[t];
    for (int i = 0; i < QD; ++i) acc += x[i] * W1[i * 64 + t];
    h[t] = fmaxf(acc, 0.f);
    __syncthreads();
    for (int s = 0; s < 8; ++s) {
        int o = t + 64 * s;
        float a = b2[o];
        for (int i = 0; i < 64; ++i) a += h[i] * W2[i * 512 + o];
        qenc[row * 512 + o] = a;
    }
}

// -------------------------------------------------------------- attention ---
// Block = (b, chunk of 512 keys). 4 waves = 4 heads. Raw fp32 K/V staged
// async via global_load_lds (double-buffered, 1 barrier/tile, T3-minimum
// schedule); bf16 truncation-split happens at use, in registers. S^T =
// mfma(K,Q) 3-term; P->A-frags via cross-half shfl exchange; O += mfma(P,V).
// V cols 128/129 via exact fp32 tail. T13 defer-max (THR=8) skips O-rescale.
__global__ __launch_bounds__(256, 2) void attn_kernel(
        const float* __restrict__ Kg, const float* __restrict__ Vg,
        const int* __restrict__ maskg, const float* __restrict__ qenc,
        float* __restrict__ part) {
    int blk = blockIdx.x;
    int c = blk & (CT - 1);
    int b = blk / CT;
    int tid = threadIdx.x;
    int wid = tid >> 6;            // head
    int lane = tid & 63;
    int l31 = lane & 31;
    int lh = lane >> 5;

    // raw fp32 tiles, [buf][kst|g][lane-linear]
    __shared__ __align__(16) float KrA[2][8][64][4];   // 16 KB  cols kst*16+lh*8..+3
    __shared__ __align__(16) float KrB[2][8][64][4];   // 16 KB  cols kst*16+lh*8+4..+7
    __shared__ __align__(16) float Vr[2][8][8][64];    // 32 KB  [g][j][lane]
    __shared__ float Vtc[2][2][64];                    // V cols 128,129 (rows dup'd)
    __shared__ int   mskr[2][64];
    __shared__ float r_lds[4][32];

    const float* Kb = Kg + (size_t)b * NN * KD;
    const float* Vb = Vg + (size_t)b * NN * VD;
    const int*   Mb = maskg + b * NN;

    const int kst0 = wid, kst1 = wid + 4;
    const int g0 = wid, g1 = wid + 4;

    auto stage = [&](int T, int buf) {
        int n0 = c * NCH + T * 32;
        const float* ka = Kb + (size_t)(n0 + l31) * KD + kst0 * 16 + lh * 8;
        cp16(&KrA[buf][kst0][0][0], ka);
        cp16(&KrB[buf][kst0][0][0], ka + 4);
        const float* kb2 = Kb + (size_t)(n0 + l31) * KD + kst1 * 16 + lh * 8;
        cp16(&KrA[buf][kst1][0][0], kb2);
        cp16(&KrB[buf][kst1][0][0], kb2 + 4);
        {
            const float* vsrc = Vb + (size_t)(n0 + (g0 & 1) * 16 + lh * 8) * VD
                                + (g0 >> 1) * 32 + l31;
            #pragma unroll
            for (int j = 0; j < 8; ++j)
                cp4(&Vr[buf][g0][j][0], vsrc + (size_t)j * VD);
        }
        {
            const float* vsrc = Vb + (size_t)(n0 + (g1 & 1) * 16 + lh * 8) * VD
                                + (g1 >> 1) * 32 + l31;
            #pragma unroll
            for (int j = 0; j < 8; ++j)
                cp4(&Vr[buf][g1][j][0], vsrc + (size_t)j * VD);
        }
        if (wid == 0) {
            cp4(&Vtc[buf][0][0], Vb + (size_t)(n0 + l31) * VD + 128);
            cp4(&Vtc[buf][1][0], Vb + (size_t)(n0 + l31) * VD + 129);
        }
        if (wid == 1) {
            cp4((float*)&mskr[buf][0], (const float*)(Mb + n0 + l31));
        }
    };

    stage(0, 0);                   // async; flight hidden under Q prep

    // ---- Q fragments (hi/lo truncation split), 8 k-steps
    bf16x8 qh[8], ql[8];
    {
        const float* qrow = qenc + (size_t)(b * JJ + l31) * 512 + wid * KD + lh * 8;
        #pragma unroll
        for (int kst = 0; kst < 8; ++kst) {
            float4 qa = *(const float4*)(qrow + kst * 16);
            float4 qb = *(const float4*)(qrow + kst * 16 + 4);
            split8(qa, qb, &qh[kst], &ql[kst]);
        }
    }

    f32x16 O[4];
    #pragma unroll
    for (int vt = 0; vt < 4; ++vt)
        #pragma unroll
        for (int r = 0; r < 16; ++r) O[vt][r] = 0.f;
    float acct0 = 0.f, acct1 = 0.f;
    float m_run = -1e30f, l_run = 0.f;

    __syncthreads();               // implicit vmcnt(0): buf0 landed

    for (int t = 0; t < TIL; ++t) {
        int cur = t & 1;
        if (t + 1 < TIL) stage(t + 1, cur ^ 1);   // async into idle buffer

        int mv = mskr[cur][lane];
        unsigned int mword = (unsigned int)__ballot(mv != 0);

        // ---- S^T = K . Q, two independent 12-MFMA chains
        f32x16 S0, S1;
        #pragma unroll
        for (int r = 0; r < 16; ++r) { S0[r] = 0.f; S1[r] = 0.f; }
        #pragma unroll
        for (int kst = 0; kst < 4; ++kst) {
            float4 a = *(const float4*)&KrA[cur][kst][lane][0];
            float4 bb = *(const float4*)&KrB[cur][kst][lane][0];
            bf16x8 kh, kl;
            split8(a, bb, &kh, &kl);
            S0 = __builtin_amdgcn_mfma_f32_32x32x16_bf16(kh, qh[kst], S0, 0, 0, 0);
            S0 = __builtin_amdgcn_mfma_f32_32x32x16_bf16(kh, ql[kst], S0, 0, 0, 0);
            S0 = __builtin_amdgcn_mfma_f32_32x32x16_bf16(kl, qh[kst], S0, 0, 0, 0);
        }
        #pragma unroll
        for (int kst = 4; kst < 8; ++kst) {
            float4 a = *(const float4*)&KrA[cur][kst][lane][0];
            float4 bb = *(const float4*)&KrB[cur][kst][lane][0];
            bf16x8 kh, kl;
            split8(a, bb, &kh, &kl);
            S1 = __builtin_amdgcn_mfma_f32_32x32x16_bf16(kh, qh[kst], S1, 0, 0, 0);
            S1 = __builtin_amdgcn_mfma_f32_32x32x16_bf16(kh, ql[kst], S1, 0, 0, 0);
            S1 = __builtin_amdgcn_mfma_f32_32x32x16_bf16(kl, qh[kst], S1, 0, 0, 0);
        }

        // ---- mask + scale, defer-max online softmax (q = lane&31 column)
        const float sc = 0.08838834764831845f;
        float sp[16];
        float rm = -1e30f;
        #pragma unroll
        for (int r = 0; r < 16; ++r) {
            int key = (r & 3) + 8 * (r >> 2) + (lh << 2);
            float s = ((mword >> key) & 1u) ? -1e30f : (S0[r] + S1[r]) * sc;
            sp[r] = s;
            rm = fmaxf(rm, s);
        }
        rm = fmaxf(rm, __shfl_xor(rm, 32));
        if (!__all(rm <= m_run + 8.f)) {          // T13: rescale only on growth >8
            float mn = fmaxf(m_run, rm);
            float rs = __expf(m_run - mn);
            m_run = mn;
            l_run *= rs; acct0 *= rs; acct1 *= rs;
            if (lane < 32) r_lds[wid][lane] = rs;
            float rr[16];
            #pragma unroll
            for (int r = 0; r < 16; ++r)
                rr[r] = r_lds[wid][(r & 3) + 8 * (r >> 2) + (lh << 2)];
            #pragma unroll
            for (int vt = 0; vt < 4; ++vt)
                #pragma unroll
                for (int r = 0; r < 16; ++r) O[vt][r] *= rr[r];
        }
        float ps = 0.f;
        #pragma unroll
        for (int r = 0; r < 16; ++r) {
            float p = __expf(sp[r] - m_run);      // bounded by e^8
            sp[r] = p;
            ps += p;
        }
        ps += __shfl_xor(ps, 32);
        l_run += ps;

        // ---- fp32 tail: out[q][128|129] += p * V[n][128|129]
        #pragma unroll
        for (int r = 0; r < 16; ++r) {
            int key = (r & 3) + 8 * (r >> 2) + (lh << 2);
            acct0 += sp[r] * Vtc[cur][0][key];
            acct1 += sp[r] * Vtc[cur][1][key];
        }

        // ---- P -> A-fragments (hi/lo) via cross-half exchange
        bf16x8 pah[2], pal[2];
        #pragma unroll
        for (int ks = 0; ks < 2; ++ks) {
            int b0 = 8 * ks;
            unsigned int wh[4], wl[4];
            #pragma unroll
            for (int i = 0; i < 4; ++i) {
                float p0 = sp[b0 + 2 * i], p1 = sp[b0 + 2 * i + 1];
                wh[i] = packhi(p0, p1);
                wl[i] = packhi(p0 - truncbf(p0), p1 - truncbf(p1));
            }
            unsigned int s0h = __shfl_xor(wh[0], 32), s1h = __shfl_xor(wh[1], 32);
            unsigned int s2h = __shfl_xor(wh[2], 32), s3h = __shfl_xor(wh[3], 32);
            unsigned int s0l = __shfl_xor(wl[0], 32), s1l = __shfl_xor(wl[1], 32);
            unsigned int s2l = __shfl_xor(wl[2], 32), s3l = __shfl_xor(wl[3], 32);
            FW4 PH, PL;
            PH.u[0] = lh ? s2h : wh[0];
            PH.u[1] = lh ? s3h : wh[1];
            PH.u[2] = lh ? wh[2] : s0h;
            PH.u[3] = lh ? wh[3] : s1h;
            PL.u[0] = lh ? s2l : wl[0];
            PL.u[1] = lh ? s3l : wl[1];
            PL.u[2] = lh ? wl[2] : s0l;
            PL.u[3] = lh ? wl[3] : s1l;
            pah[ks] = PH.v; pal[ks] = PL.v;
        }

        // ---- O += P . V (3-term split, 4 independent chains)
        #pragma unroll
        for (int ks = 0; ks < 2; ++ks) {
            #pragma unroll
            for (int vt = 0; vt < 4; ++vt) {
                int g = vt * 2 + ks;
                float4 va = {Vr[cur][g][0][lane], Vr[cur][g][1][lane],
                             Vr[cur][g][2][lane], Vr[cur][g][3][lane]};
                float4 vb2 = {Vr[cur][g][4][lane], Vr[cur][g][5][lane],
                              Vr[cur][g][6][lane], Vr[cur][g][7][lane]};
                bf16x8 vh, vl;
                split8(va, vb2, &vh, &vl);
                O[vt] = __builtin_amdgcn_mfma_f32_32x32x16_bf16(pah[ks], vh, O[vt], 0, 0, 0);
                O[vt] = __builtin_amdgcn_mfma_f32_32x32x16_bf16(pal[ks], vh, O[vt], 0, 0, 0);
                O[vt] = __builtin_amdgcn_mfma_f32_32x32x16_bf16(pah[ks], vl, O[vt], 0, 0, 0);
            }
        }

        __syncthreads();           // drains stage(t+1) vmem + ends buf reads
    }

    // ---- write partials
    float* P = part + (size_t)((b * HH + wid) * CT + c) * PSTRIDE;
    if (lane < 32) { P[lane] = m_run; P[JJ + lane] = l_run; }
    float* A = P + 2 * JJ;
    #pragma unroll
    for (int vt = 0; vt < 4; ++vt) {
        #pragma unroll
        for (int r = 0; r < 16; ++r) {
            int q = (r & 3) + 8 * (r >> 2) + (lh << 2);
            A[q * VD + vt * 32 + l31] = O[vt][r];
        }
    }
    float t0 = acct0 + __shfl_xor(acct0, 32);
    float t1 = acct1 + __shfl_xor(acct1, 32);
    if (lh == 0) {
        A[l31 * VD + 128] = t0;
        A[l31 * VD + 129] = t1;
    }
}

// -------------------------------------------- fused combine + output MLP ----
__global__ __launch_bounds__(64) void comb_mlp_kernel(
        const float* __restrict__ part,
        const float* __restrict__ W3, const float* __restrict__ b3,
        const float* __restrict__ W4, const float* __restrict__ b4,
        const float* __restrict__ W5, const float* __restrict__ b5,
        float* __restrict__ out) {
    int row = blockIdx.x;          // b*J + j
    int b = row >> 5;
    int j = row & 31;
    int t = threadIdx.x;
    __shared__ float w_s[HH][CT];
    __shared__ float x[HH * VD];
    __shared__ float h1[64];
    __shared__ float h2[32];

    if (t < HH * CT) {
        int h = t / CT, cc = t % CT;
        const float* P = part + (size_t)((b * HH + h) * CT + cc) * PSTRIDE;
        float m = P[j];
        float l = P[JJ + j];
        float mm = m;
        #pragma unroll
        for (int s = 1; s < CT; s <<= 1) mm = fmaxf(mm, __shfl_xor(mm, s));
        float e = __expf(m - mm);
        float L = l * e;
        #pragma unroll
        for (int s = 1; s < CT; s <<= 1) L += __shfl_xor(L, s);
        w_s[h][cc] = (L > 0.f) ? e / L : 0.f;
    }
    __syncthreads();

    for (int idx = t; idx < HH * VD; idx += 64) {
        int h = idx / VD, v = idx - h * VD;
        const float* A = part + (size_t)(b * HH + h) * CT * PSTRIDE + 2 * JJ + j * VD + v;
        float o = 0.f;
        #pragma unroll 4
        for (int cc = 0; cc < CT; ++cc) o += w_s[h][cc] * A[(size_t)cc * PSTRIDE];
        x[idx] = o;
    }
    __syncthreads();

    float a = b3[t];
    #pragma unroll 8
    for (int i = 0; i < HH * VD; ++i) a += x[i] * W3[i * 64 + t];
    h1[t] = fmaxf(a, 0.f);
    __syncthreads();
    if (t < 32) {
        float a2 = b4[t];
        for (int i = 0; i < 64; ++i) a2 += h1[i] * W4[i * 32 + t];
        h2[t] = fmaxf(a2, 0.f);
    }
    __syncthreads();
    if (t == 0) {
        float a3 = b5[0];
        for (int i = 0; i < 32; ++i) a3 += h2[i] * W5[i];
        out[row] = a3;
    }
}

extern "C" void kernel_launch(void* const* d_in, const int* in_sizes, int n_in,
                              void* d_out, int out_size, void* d_ws, size_t ws_size,
                              hipStream_t stream) {
    const float* jq = (const float*)d_in[0];
    const float* Kg = (const float*)d_in[1];
    const float* Vg = (const float*)d_in[2];
    const int* mask = (const int*)d_in[3];
    const float* W1 = (const float*)d_in[4];
    const float* b1 = (const float*)d_in[5];
    const float* W2 = (const float*)d_in[6];
    const float* b2 = (const float*)d_in[7];
    const float* W3 = (const float*)d_in[8];
    const float* b3 = (const float*)d_in[9];
    const float* W4 = (const float*)d_in[10];
    const float* b4 = (const float*)d_in[11];
    const float* W5 = (const float*)d_in[12];
    const float* b5 = (const float*)d_in[13];
    float* out = (float*)d_out;

    float* ws = (float*)d_ws;
    float* qenc = ws;                                   // B*J*512 floats
    float* part = qenc + (size_t)BB * JJ * HH * KD;     // B*H*CT*PSTRIDE floats

    enc_kernel<<<BB * JJ, 64, 0, stream>>>(jq, W1, b1, W2, b2, qenc);
    attn_kernel<<<BB * CT, 256, 0, stream>>>(Kg, Vg, mask, qenc, part);
    comb_mlp_kernel<<<BB * JJ, 64, 0, stream>>>(part, W3, b3, W4, b4, W5, b5, out);
}

// Round 8
// 118.793 us; speedup vs baseline: 2.7246x; 1.4527x over previous
//
#include <hip/hip_runtime.h>
#include <hip/hip_bf16.h>

#define BB 64
#define JJ 32
#define NN 4096
#define QD 130
#define KD 128
#define VD 130
#define HH 4
#define CT 8
#define NCH (NN / CT)                 // 512
#define TIL (NCH / 32)                // 16
#define PSTRIDE (JJ + JJ + JJ * VD)   // 4224 floats per partial block

typedef __attribute__((ext_vector_type(8)))  __bf16 bf16x8;
typedef __attribute__((ext_vector_type(16))) float  f32x16;

union FW4 { unsigned int u[4]; bf16x8 v; };

#define SEL_HI 0x07060302u

__device__ __forceinline__ unsigned int packhi(float f0, float f1) {
    // {hi16(f1), hi16(f0)} in one v_perm_b32
    return __builtin_amdgcn_perm(__float_as_uint(f1), __float_as_uint(f0), SEL_HI);
}
__device__ __forceinline__ float truncbf(float f) {
    return __uint_as_float(__float_as_uint(f) & 0xFFFF0000u);
}
// truncation split: 8 floats -> hi/lo bf16x8 planes (f = h + l + O(2^-17))
__device__ __forceinline__ void split8(float4 a, float4 b, bf16x8* h, bf16x8* l) {
    FW4 H, L;
    H.u[0] = packhi(a.x, a.y);
    H.u[1] = packhi(a.z, a.w);
    H.u[2] = packhi(b.x, b.y);
    H.u[3] = packhi(b.z, b.w);
    L.u[0] = packhi(a.x - truncbf(a.x), a.y - truncbf(a.y));
    L.u[1] = packhi(a.z - truncbf(a.z), a.w - truncbf(a.w));
    L.u[2] = packhi(b.x - truncbf(b.x), b.y - truncbf(b.y));
    L.u[3] = packhi(b.z - truncbf(b.z), b.w - truncbf(b.w));
    *h = H.v; *l = L.v;
}

// ---------------------------------------------------------------- encoder ---
__global__ __launch_bounds__(64) void enc_kernel(
        const float* __restrict__ jq,
        const float* __restrict__ W1, const float* __restrict__ b1,
        const float* __restrict__ W2, const float* __restrict__ b2,
        float* __restrict__ qenc) {
    int row = blockIdx.x;          // b*J + j
    int t = threadIdx.x;           // 0..63
    __shared__ float x[QD];
    __shared__ float h[64];
    for (int i = t; i < QD; i += 64) x[i] = jq[row * QD + i];
    __syncthreads();
    float a0 = 0.f, a1 = 0.f;
    for (int i = 0; i < QD - 1; i += 2) {     // 130 = 2*65, 2 chains
        a0 += x[i] * W1[i * 64 + t];
        a1 += x[i + 1] * W1[(i + 1) * 64 + t];
    }
    h[t] = fmaxf(b1[t] + a0 + a1, 0.f);
    __syncthreads();
    float a[8];
    #pragma unroll
    for (int s = 0; s < 8; ++s) a[s] = b2[t + 64 * s];
    for (int i = 0; i < 64; ++i) {
        float hv = h[i];
        #pragma unroll
        for (int s = 0; s < 8; ++s) a[s] += hv * W2[i * 512 + t + 64 * s];
    }
    #pragma unroll
    for (int s = 0; s < 8; ++s) qenc[row * 512 + t + 64 * s] = a[s];
}

// -------------------------------------------------------------- attention ---
// Block = (b, chunk of 512 keys), 512 threads = 8 waves.
// Waves 0-3: compute (head = wid) — S^T = mfma(K,Q) 3-term split-bf16,
//   in-register online softmax (defer-max THR=8), P->A-frag exchange,
//   O += mfma(P,V), fp32 tail for V cols 128/129.
// Waves 4-7: stagers — depth-2 register bundles of raw fp32 K/V, split
//   ONCE to bf16 hi/lo planes, ds_write into double-buffered LDS. The
//   barrier vmcnt-drain stall lives in the stager timeline, hidden under
//   compute (producer/consumer; split redundancy 4x -> 1x).
__global__ __launch_bounds__(512, 2) void attn_kernel(
        const float* __restrict__ Kg, const float* __restrict__ Vg,
        const int* __restrict__ maskg, const float* __restrict__ qenc,
        float* __restrict__ part) {
    int blk = blockIdx.x;
    int c = blk & (CT - 1);
    int b = blk / CT;
    int tid = threadIdx.x;
    int wid = tid >> 6;
    int lane = tid & 63;
    int l31 = lane & 31;
    int lh = lane >> 5;

    // bf16 fragment-linear LDS, double-buffered: [buf][plane][kst|g][lane][8]
    __shared__ __align__(16) __bf16 Kbf[2][2][8][64][8];   // 32 KB
    __shared__ __align__(16) __bf16 Vbf[2][2][8][64][8];   // 32 KB
    __shared__ float Vtc[2][2][32];                        // V cols 128,129
    __shared__ int   msks[2][32];
    __shared__ float r_lds[4][32];

    const float* Kb = Kg + (size_t)b * NN * KD;
    const float* Vb = Vg + (size_t)b * NN * VD;
    const int*   Mb = maskg + b * NN;

    if (wid >= 4) {
        // ================================ stager ================================
        int sid = tid - 256;           // 0..255
        int sl = sid & 63;
        int grp = sid >> 6;            // 0..3
        const int kstA = grp, kstB = grp + 4;
        const int gB = grp + 4;
        const int vAcol = (grp >> 1) * 32 + (sl & 31);
        const int vArow = (grp & 1) * 16 + (sl >> 5) * 8;
        const int vBcol = (gB >> 1) * 32 + (sl & 31);
        const int vBrow = (gB & 1) * 16 + (sl >> 5) * 8;

        float k0a[8], k0b[8], v0a[8], v0b[8]; float2 vt0 = {0, 0}; int mk0 = 0;
        float k1a[8], k1b[8], v1a[8], v1b[8]; float2 vt1 = {0, 0}; int mk1 = 0;

        auto sload = [&](float* kA, float* kB2, float* vA, float* vB2,
                         float2& vt, int& mk, int T) {
            int n0 = c * NCH + T * 32;
            const float* ka = Kb + (size_t)(n0 + (sl & 31)) * KD + kstA * 16 + (sl >> 5) * 8;
            *(float4*)&kA[0] = *(const float4*)ka;
            *(float4*)&kA[4] = *(const float4*)(ka + 4);
            const float* kb2 = Kb + (size_t)(n0 + (sl & 31)) * KD + kstB * 16 + (sl >> 5) * 8;
            *(float4*)&kB2[0] = *(const float4*)kb2;
            *(float4*)&kB2[4] = *(const float4*)(kb2 + 4);
            const float* va = Vb + (size_t)(n0 + vArow) * VD + vAcol;
            #pragma unroll
            for (int j = 0; j < 8; ++j) vA[j] = va[(size_t)j * VD];
            const float* vb = Vb + (size_t)(n0 + vBrow) * VD + vBcol;
            #pragma unroll
            for (int j = 0; j < 8; ++j) vB2[j] = vb[(size_t)j * VD];
            if (sid < 32) {
                vt = *(const float2*)(Vb + (size_t)(n0 + sid) * VD + 128);
                mk = Mb[n0 + sid];
            }
        };
        auto ssplit = [&](float* kA, float* kB2, float* vA, float* vB2,
                          float2 vt, int mk, int BUF) {
            bf16x8 h, l;
            split8(*(float4*)&kA[0], *(float4*)&kA[4], &h, &l);
            *(bf16x8*)&Kbf[BUF][0][kstA][sl][0] = h;
            *(bf16x8*)&Kbf[BUF][1][kstA][sl][0] = l;
            split8(*(float4*)&kB2[0], *(float4*)&kB2[4], &h, &l);
            *(bf16x8*)&Kbf[BUF][0][kstB][sl][0] = h;
            *(bf16x8*)&Kbf[BUF][1][kstB][sl][0] = l;
            split8(*(float4*)&vA[0], *(float4*)&vA[4], &h, &l);
            *(bf16x8*)&Vbf[BUF][0][grp][sl][0] = h;
            *(bf16x8*)&Vbf[BUF][1][grp][sl][0] = l;
            split8(*(float4*)&vB2[0], *(float4*)&vB2[4], &h, &l);
            *(bf16x8*)&Vbf[BUF][0][gB][sl][0] = h;
            *(bf16x8*)&Vbf[BUF][1][gB][sl][0] = l;
            if (sid < 32) {
                Vtc[BUF][0][sid] = vt.x;
                Vtc[BUF][1][sid] = vt.y;
                msks[BUF][sid] = mk;
            }
        };

        sload(k0a, k0b, v0a, v0b, vt0, mk0, 0);
        sload(k1a, k1b, v1a, v1b, vt1, mk1, 1);
        ssplit(k0a, k0b, v0a, v0b, vt0, mk0, 0);
        __syncthreads();               // tile 0 published

        for (int t = 0; t < TIL; ++t) {
            if ((t & 1) == 0) {
                if (t + 2 < TIL) sload(k0a, k0b, v0a, v0b, vt0, mk0, t + 2);
                ssplit(k1a, k1b, v1a, v1b, vt1, mk1, 1);      // tile t+1 (odd)
            } else {
                if (t + 2 < TIL) sload(k1a, k1b, v1a, v1b, vt1, mk1, t + 2);
                if (t + 1 < TIL) ssplit(k0a, k0b, v0a, v0b, vt0, mk0, 0);  // tile t+1 (even)
            }
            __syncthreads();
        }
    } else {
        // ================================ compute ===============================
        // ---- Q fragments (hi/lo truncation split), 8 k-steps
        bf16x8 qh[8], ql[8];
        {
            const float* qrow = qenc + (size_t)(b * JJ + l31) * 512 + wid * KD + lh * 8;
            #pragma unroll
            for (int kst = 0; kst < 8; ++kst) {
                float4 qa = *(const float4*)(qrow + kst * 16);
                float4 qb = *(const float4*)(qrow + kst * 16 + 4);
                split8(qa, qb, &qh[kst], &ql[kst]);
            }
        }

        f32x16 O[4];
        #pragma unroll
        for (int vt = 0; vt < 4; ++vt)
            #pragma unroll
            for (int r = 0; r < 16; ++r) O[vt][r] = 0.f;
        float acct0 = 0.f, acct1 = 0.f;
        float m_run = -1e30f, l_run = 0.f;

        __syncthreads();               // tile 0 published

        for (int t = 0; t < TIL; ++t) {
            int cur = t & 1;

            int mv = msks[cur][l31];
            unsigned int mword = (unsigned int)__ballot(mv != 0);

            // ---- S^T = K . Q, two independent 12-MFMA chains
            f32x16 S0, S1;
            #pragma unroll
            for (int r = 0; r < 16; ++r) { S0[r] = 0.f; S1[r] = 0.f; }
            #pragma unroll
            for (int kst = 0; kst < 4; ++kst) {
                bf16x8 kh = *(const bf16x8*)&Kbf[cur][0][kst][lane][0];
                bf16x8 kl = *(const bf16x8*)&Kbf[cur][1][kst][lane][0];
                S0 = __builtin_amdgcn_mfma_f32_32x32x16_bf16(kh, qh[kst], S0, 0, 0, 0);
                S0 = __builtin_amdgcn_mfma_f32_32x32x16_bf16(kh, ql[kst], S0, 0, 0, 0);
                S0 = __builtin_amdgcn_mfma_f32_32x32x16_bf16(kl, qh[kst], S0, 0, 0, 0);
            }
            #pragma unroll
            for (int kst = 4; kst < 8; ++kst) {
                bf16x8 kh = *(const bf16x8*)&Kbf[cur][0][kst][lane][0];
                bf16x8 kl = *(const bf16x8*)&Kbf[cur][1][kst][lane][0];
                S1 = __builtin_amdgcn_mfma_f32_32x32x16_bf16(kh, qh[kst], S1, 0, 0, 0);
                S1 = __builtin_amdgcn_mfma_f32_32x32x16_bf16(kh, ql[kst], S1, 0, 0, 0);
                S1 = __builtin_amdgcn_mfma_f32_32x32x16_bf16(kl, qh[kst], S1, 0, 0, 0);
            }

            // ---- mask + scale, defer-max online softmax (q = lane&31 column)
            const float sc = 0.08838834764831845f;
            float sp[16];
            float rm = -1e30f;
            #pragma unroll
            for (int r = 0; r < 16; ++r) {
                int key = (r & 3) + 8 * (r >> 2) + (lh << 2);
                float s = ((mword >> key) & 1u) ? -1e30f : (S0[r] + S1[r]) * sc;
                sp[r] = s;
                rm = fmaxf(rm, s);
            }
            rm = fmaxf(rm, __shfl_xor(rm, 32));
            if (!__all(rm <= m_run + 8.f)) {      // T13: rescale only on growth >8
                float mn = fmaxf(m_run, rm);
                float rs = __expf(m_run - mn);
                m_run = mn;
                l_run *= rs; acct0 *= rs; acct1 *= rs;
                if (lane < 32) r_lds[wid][lane] = rs;
                float rr[16];
                #pragma unroll
                for (int r = 0; r < 16; ++r)
                    rr[r] = r_lds[wid][(r & 3) + 8 * (r >> 2) + (lh << 2)];
                #pragma unroll
                for (int vt = 0; vt < 4; ++vt)
                    #pragma unroll
                    for (int r = 0; r < 16; ++r) O[vt][r] *= rr[r];
            }
            float ps = 0.f;
            #pragma unroll
            for (int r = 0; r < 16; ++r) {
                float p = __expf(sp[r] - m_run);  // bounded by e^8
                sp[r] = p;
                ps += p;
            }
            ps += __shfl_xor(ps, 32);
            l_run += ps;

            // ---- fp32 tail: out[q][128|129] += p * V[n][128|129]
            #pragma unroll
            for (int r = 0; r < 16; ++r) {
                int key = (r & 3) + 8 * (r >> 2) + (lh << 2);
                acct0 += sp[r] * Vtc[cur][0][key];
                acct1 += sp[r] * Vtc[cur][1][key];
            }

            // ---- P -> A-fragments (hi/lo) via cross-half exchange
            bf16x8 pah[2], pal[2];
            #pragma unroll
            for (int ks = 0; ks < 2; ++ks) {
                int b0 = 8 * ks;
                unsigned int wh[4], wl[4];
                #pragma unroll
                for (int i = 0; i < 4; ++i) {
                    float p0 = sp[b0 + 2 * i], p1 = sp[b0 + 2 * i + 1];
                    wh[i] = packhi(p0, p1);
                    wl[i] = packhi(p0 - truncbf(p0), p1 - truncbf(p1));
                }
                unsigned int s0h = __shfl_xor(wh[0], 32), s1h = __shfl_xor(wh[1], 32);
                unsigned int s2h = __shfl_xor(wh[2], 32), s3h = __shfl_xor(wh[3], 32);
                unsigned int s0l = __shfl_xor(wl[0], 32), s1l = __shfl_xor(wl[1], 32);
                unsigned int s2l = __shfl_xor(wl[2], 32), s3l = __shfl_xor(wl[3], 32);
                FW4 PH, PL;
                PH.u[0] = lh ? s2h : wh[0];
                PH.u[1] = lh ? s3h : wh[1];
                PH.u[2] = lh ? wh[2] : s0h;
                PH.u[3] = lh ? wh[3] : s1h;
                PL.u[0] = lh ? s2l : wl[0];
                PL.u[1] = lh ? s3l : wl[1];
                PL.u[2] = lh ? wl[2] : s0l;
                PL.u[3] = lh ? wl[3] : s1l;
                pah[ks] = PH.v; pal[ks] = PL.v;
            }

            // ---- O += P . V (3-term split, b128 V reads)
            #pragma unroll
            for (int ks = 0; ks < 2; ++ks) {
                #pragma unroll
                for (int vt = 0; vt < 4; ++vt) {
                    int g = vt * 2 + ks;
                    bf16x8 vh = *(const bf16x8*)&Vbf[cur][0][g][lane][0];
                    bf16x8 vl = *(const bf16x8*)&Vbf[cur][1][g][lane][0];
                    O[vt] = __builtin_amdgcn_mfma_f32_32x32x16_bf16(pah[ks], vh, O[vt], 0, 0, 0);
                    O[vt] = __builtin_amdgcn_mfma_f32_32x32x16_bf16(pal[ks], vh, O[vt], 0, 0, 0);
                    O[vt] = __builtin_amdgcn_mfma_f32_32x32x16_bf16(pah[ks], vl, O[vt], 0, 0, 0);
                }
            }

            __syncthreads();
        }

        // ---- write partials
        float* P = part + (size_t)((b * HH + wid) * CT + c) * PSTRIDE;
        if (lane < 32) { P[lane] = m_run; P[JJ + lane] = l_run; }
        float* A = P + 2 * JJ;
        #pragma unroll
        for (int vt = 0; vt < 4; ++vt) {
            #pragma unroll
            for (int r = 0; r < 16; ++r) {
                int q = (r & 3) + 8 * (r >> 2) + (lh << 2);
                A[q * VD + vt * 32 + l31] = O[vt][r];
            }
        }
        float t0 = acct0 + __shfl_xor(acct0, 32);
        float t1 = acct1 + __shfl_xor(acct1, 32);
        if (lh == 0) {
            A[l31 * VD + 128] = t0;
            A[l31 * VD + 129] = t1;
        }
    }
}

// -------------------------------------------- fused combine + output MLP ----
__global__ __launch_bounds__(64) void comb_mlp_kernel(
        const float* __restrict__ part,
        const float* __restrict__ W3, const float* __restrict__ b3,
        const float* __restrict__ W4, const float* __restrict__ b4,
        const float* __restrict__ W5, const float* __restrict__ b5,
        float* __restrict__ out) {
    int row = blockIdx.x;          // b*J + j
    int b = row >> 5;
    int j = row & 31;
    int t = threadIdx.x;
    __shared__ float w_s[HH][CT];
    __shared__ float x[HH * VD];
    __shared__ float h1[64];
    __shared__ float h2[32];

    if (t < HH * CT) {
        int h = t / CT, cc = t % CT;
        const float* P = part + (size_t)((b * HH + h) * CT + cc) * PSTRIDE;
        float m = P[j];
        float l = P[JJ + j];
        float mm = m;
        #pragma unroll
        for (int s = 1; s < CT; s <<= 1) mm = fmaxf(mm, __shfl_xor(mm, s));
        float e = __expf(m - mm);
        float L = l * e;
        #pragma unroll
        for (int s = 1; s < CT; s <<= 1) L += __shfl_xor(L, s);
        w_s[h][cc] = (L > 0.f) ? e / L : 0.f;
    }
    __syncthreads();

    for (int idx = t; idx < HH * VD; idx += 64) {
        int h = idx / VD, v = idx - h * VD;
        const float* A = part + (size_t)(b * HH + h) * CT * PSTRIDE + 2 * JJ + j * VD + v;
        float o = 0.f;
        #pragma unroll 4
        for (int cc = 0; cc < CT; ++cc) o += w_s[h][cc] * A[(size_t)cc * PSTRIDE];
        x[idx] = o;
    }
    __syncthreads();

    float a0 = 0.f, a1 = 0.f, a2 = 0.f, a3 = 0.f;
    for (int i = 0; i < HH * VD; i += 4) {     // 520 = 4*130, 4 chains
        a0 += x[i] * W3[i * 64 + t];
        a1 += x[i + 1] * W3[(i + 1) * 64 + t];
        a2 += x[i + 2] * W3[(i + 2) * 64 + t];
        a3 += x[i + 3] * W3[(i + 3) * 64 + t];
    }
    h1[t] = fmaxf(b3[t] + (a0 + a1) + (a2 + a3), 0.f);
    __syncthreads();
    if (t < 32) {
        float c0 = 0.f, c1 = 0.f;
        for (int i = 0; i < 64; i += 2) {
            c0 += h1[i] * W4[i * 32 + t];
            c1 += h1[i + 1] * W4[(i + 1) * 32 + t];
        }
        h2[t] = fmaxf(b4[t] + c0 + c1, 0.f);
    }
    __syncthreads();
    if (t == 0) {
        float a3f = b5[0];
        for (int i = 0; i < 32; ++i) a3f += h2[i] * W5[i];
        out[row] = a3f;
    }
}

extern "C" void kernel_launch(void* const* d_in, const int* in_sizes, int n_in,
                              void* d_out, int out_size, void* d_ws, size_t ws_size,
                              hipStream_t stream) {
    const float* jq = (const float*)d_in[0];
    const float* Kg = (const float*)d_in[1];
    const float* Vg = (const float*)d_in[2];
    const int* mask = (const int*)d_in[3];
    const float* W1 = (const float*)d_in[4];
    const float* b1 = (const float*)d_in[5];
    const float* W2 = (const float*)d_in[6];
    const float* b2 = (const float*)d_in[7];
    const float* W3 = (const float*)d_in[8];
    const float* b3 = (const float*)d_in[9];
    const float* W4 = (const float*)d_in[10];
    const float* b4 = (const float*)d_in[11];
    const float* W5 = (const float*)d_in[12];
    const float* b5 = (const float*)d_in[13];
    float* out = (float*)d_out;

    float* ws = (float*)d_ws;
    float* qenc = ws;                                   // B*J*512 floats
    float* part = qenc + (size_t)BB * JJ * HH * KD;     // B*H*CT*PSTRIDE floats

    enc_kernel<<<BB * JJ, 64, 0, stream>>>(jq, W1, b1, W2, b2, qenc);
    attn_kernel<<<BB * CT, 512, 0, stream>>>(Kg, Vg, mask, qenc, part);
    comb_mlp_kernel<<<BB * JJ, 64, 0, stream>>>(part, W3, b3, W4, b4, W5, b5, out);
}